// Round 8
// baseline (299.231 us; speedup 1.0000x reference)
//
#include <hip/hip_runtime.h>

#define K_TAPS   61
#define R_OUT    16
#define BLOCK    256
#define TILE_OUT (BLOCK * R_OUT)             // 4096 outputs per block
#define TILE_IN  (TILE_OUT + K_TAPS - 1)     // 4156 floats staged (%4==0)
#define TILE_IN4 (TILE_IN / 4)               // 1039 float4 loads
#define SUBP     261                         // sub-array stride (>=260, odd)
#define WINP     (R_OUT + K_TAPS - 1)        // 76 window positions/thread

__global__ __launch_bounds__(BLOCK)
void SpikeToCalcium_conv1d_kernel(const float* __restrict__ u,
                                  const float* __restrict__ kern,
                                  float* __restrict__ out,
                                  int L, int M, long long total_in)
{
    // SoA-16: sx[(q%16)*SUBP + q/16] = tile[q]. Inner-loop reads are
    // lane-stride-4B ds_read_b32 (2 lanes/bank = free) with one VGPR
    // address and compile-time immediate offsets.
    __shared__ float sx[16 * SUBP];

    const int t          = threadIdx.x;
    const int row        = blockIdx.y;
    const int tile_start = blockIdx.x * TILE_OUT;

    // ---- Stage tile: coalesced float4 global loads, de-interleaved b32
    // LDS writes. Over-read past the row end only feeds masked outputs;
    // guard only the buffer end.
    const long long gbase = (long long)row * L + tile_start;   // L%4==0 -> aligned
    for (int v = t; v < TILE_IN4; v += BLOCK) {
        const long long g = gbase + 4LL * v;
        float4 val;
        if (g + 3 < total_in) {
            val = *reinterpret_cast<const float4*>(u + g);
        } else {
            val.x = (g + 0 < total_in) ? u[g + 0] : 0.0f;
            val.y = (g + 1 < total_in) ? u[g + 1] : 0.0f;
            val.z = (g + 2 < total_in) ? u[g + 2] : 0.0f;
            val.w = (g + 3 < total_in) ? u[g + 3] : 0.0f;
        }
        const int q0 = 4 * v;
        sx[((q0 + 0) & 15) * SUBP + ((q0 + 0) >> 4)] = val.x;
        sx[((q0 + 1) & 15) * SUBP + ((q0 + 1) >> 4)] = val.y;
        sx[((q0 + 2) & 15) * SUBP + ((q0 + 2) >> 4)] = val.z;
        sx[((q0 + 3) & 15) * SUBP + ((q0 + 3) >> 4)] = val.w;
    }
    __syncthreads();

    // ---- Window-position-ordered FMA block: x = tile[16t + p] with
    // p = 16i + m -> sub[m][t+i]. Each x feeds up to 16 FMAs then dies
    // (no sliding-window movs). Taps are wave-uniform compile-time
    // indices -> SGPR s_loads.
    float acc[R_OUT];
#pragma unroll
    for (int r = 0; r < R_OUT; ++r) acc[r] = 0.0f;

#pragma unroll
    for (int i = 0; i < 5; ++i) {
#pragma unroll
        for (int m = 0; m < 16; ++m) {
            const int p = 16 * i + m;                // window position
            if (p >= WINP) break;
            const float x = sx[m * SUBP + t + i];    // ds_read_b32, imm offset
#pragma unroll
            for (int r = 0; r < R_OUT; ++r) {
                const int k = p - r;                 // tap index (static)
                if (k >= 0 && k < K_TAPS)
                    acc[r] = fmaf(x, kern[K_TAPS - 1 - k], acc[r]);
            }
        }
    }

    // ---- Store 16 outputs as 4 float4 (aligned: M%4==0, obase%16==0).
    const int obase = tile_start + R_OUT * t;
    const long long o = (long long)row * M + obase;
#pragma unroll
    for (int gI = 0; gI < R_OUT / 4; ++gI) {
        const int ob = obase + 4 * gI;
        if (ob + 4 <= M) {
            *reinterpret_cast<float4*>(out + o + 4 * gI) =
                make_float4(acc[4 * gI + 0], acc[4 * gI + 1],
                            acc[4 * gI + 2], acc[4 * gI + 3]);
        } else {
#pragma unroll
            for (int r = 0; r < 4; ++r)
                if (ob + r < M) out[o + 4 * gI + r] = acc[4 * gI + r];
        }
    }
}

extern "C" void kernel_launch(void* const* d_in, const int* in_sizes, int n_in,
                              void* d_out, int out_size, void* d_ws, size_t ws_size,
                              hipStream_t stream) {
    const float* u    = (const float*)d_in[0];
    const float* kern = (const float*)d_in[1];
    float*       out  = (float*)d_out;

    const long long total_in = (long long)in_sizes[0];
    // total_in = R*L, out_size = R*(L-K+1)  =>  R = (total_in - out_size)/(K-1)
    const int ROWS = (int)((total_in - (long long)out_size) / (K_TAPS - 1)); // 1024
    const int L    = (int)(total_in / ROWS);                                 // 30000
    const int M    = L - K_TAPS + 1;                                         // 29940

    const int blocks_per_row = (M + TILE_OUT - 1) / TILE_OUT;  // 8
    dim3 grid(blocks_per_row, ROWS);
    SpikeToCalcium_conv1d_kernel<<<grid, BLOCK, 0, stream>>>(
        u, kern, out, L, M, total_in);
}